// Round 11
// baseline (1079.007 us; speedup 1.0000x reference)
//
#include <hip/hip_runtime.h>
#include <stdint.h>

#define WW 48
#define NQ 2304             // 48*48
#define NWT 144             // (bh, qt) tiles of 256 queries
#define NGG 8               // kc-pair groups (block covers 2 kc chunks)
#define SCL 0.51011868f     // 8^-0.5 * log2(e)  (folded so softmax = exp2)
#define SHIFT 17.312340491f // 12 * log2(e)      (fixed-shift softmax)
#define PSLAB 2304          // 9*256 floats per (gg, wt) slab

// ---------------------------------------------------------------------------
// attn: 4 queries/lane, LDS-broadcast KV (R5-verified delivery), row-split
// waves for TLP. Block = 4 waves over the SAME 256-query tile:
//   wave wv -> kc_local = wv>>1 (2 chunks of 3 key-cols), rowhalf = wv&1.
// grid 1152 = 16 bh * 9 qt * 8 gg -> 4608 waves = 4.5/SIMD (R10 was 2.25,
// occupancy 14%, VALUBusy 46% -> exposed ds_read latency; same total
// instruction count here, pure TLP fix).
// Block stages 2 chunks (48 rows x 3 cols x 64 B = 18.4 KB) cooperatively;
// keys consumed via wave-uniform ds_read_b128 broadcast (conflict-free).
// qh batched per 8-row round from global relh (L1-hot).
// logit = q.k + q.rel_w[x2-x+47] + q.rel_h[y2-y+47]; p = exp2(logit'-SHIFT)
// Two-phase in-block merge (LDS reuse, 2 regions) -> P slab per (gg, wt).
// ---------------------------------------------------------------------------
__global__ __launch_bounds__(256, 4) void attn_kernel(const float* __restrict__ in,
                                                      const float* __restrict__ relw,
                                                      const float* __restrict__ relh,
                                                      float* __restrict__ P) {
    __shared__ float4 lds[1152];       // 18432 B: staging, later 2 merge regions

    const int bx = blockIdx.x;
    const int bh = bx / 72;
    const int rem = bx - bh * 72;
    const int qt = rem >> 3;           // 0..8
    const int gg = rem & 7;            // 0..7  -> kc = gg*2 + kc_local
    const int tid = threadIdx.x;
    const int lane = tid & 63;
    const int wv = tid >> 6;           // 0..3
    const int kc_local = wv >> 1;
    const int rowhalf = wv & 1;
    const int kc = gg * 2 + kc_local;  // 0..15 (3 columns each)
    const int b = bh >> 3, h = bh & 7;
    const int wt = bh * 9 + qt;

    // ---- stage the block's 2 chunks: chunk c, 48 rows x 3 cols, [K|V] ----
    const float4* inp4 = (const float4*)in;
    for (int t = tid; t < 1152; t += 256) {
        const int chunk = t / 576, tt = t - chunk * 576;
        const int key = tt >> 2, p = tt & 3;
        const int row = key / 3, col = key - row * 3;
        const size_t px = (size_t)(b * NQ + row * 48 + (gg * 2 + chunk) * 3 + col) * 48;
        const int c4 = (p < 2) ? (16 + h * 2 + p) : (32 + h * 2 + (p - 2));
        lds[chunk * 576 + t % 576 - (tt - tt)] = inp4[px + c4];  // == lds[t]
    }

    // ---- this lane's four queries ----
    float4 qa[4], qb[4];
    int yq[4], xq[4];
#pragma unroll
    for (int j = 0; j < 4; ++j) {
        const int n = qt * 256 + j * 64 + lane;
        const int y = n / WW;
        yq[j] = y; xq[j] = n - y * WW;
        const float* qp = in + ((size_t)(b * NQ + n) * 192 + h * 8);
        float4 a = *(const float4*)qp, bb = *(const float4*)(qp + 4);
        a.x *= SCL; a.y *= SCL; a.z *= SCL; a.w *= SCL;
        bb.x *= SCL; bb.y *= SCL; bb.z *= SCL; bb.w *= SCL;
        qa[j] = a; qb[j] = bb;
    }

    // ---- qw per (query, chunk column) from global relw ----
    float qw[4][3];
#pragma unroll
    for (int j = 0; j < 4; ++j)
#pragma unroll
        for (int c = 0; c < 3; ++c) {
            const float* rw = relw + (kc * 3 + c - xq[j] + 47) * 8;
            float4 ta = *(const float4*)rw, tb = *(const float4*)(rw + 4);
            qw[j][c] = qa[j].x*ta.x + qa[j].y*ta.y + qa[j].z*ta.z + qa[j].w*ta.w
                     + qb[j].x*tb.x + qb[j].y*tb.y + qb[j].z*tb.z + qb[j].w*tb.w;
        }

    __syncthreads();   // staged KV visible to the 2 waves sharing each chunk

    float l[4] = {0, 0, 0, 0};
    float A[4][8] = {{0}};
    const float* myl = (const float*)(lds + kc_local * 576);

#pragma unroll 1
    for (int R = 0; R < 3; ++R) {
        // ---- batch qh for this round's 8 rows (global relh, L1-hot) ----
        float qh[4][8];
#pragma unroll
        for (int row = 0; row < 8; ++row) {
            const int y2 = rowhalf * 24 + R * 8 + row;
#pragma unroll
            for (int j = 0; j < 4; ++j) {
                const float* rh = relh + (y2 - yq[j] + 47) * 8;
                float4 ta = *(const float4*)rh, tb = *(const float4*)(rh + 4);
                qh[j][row] =
                    qa[j].x*ta.x + qa[j].y*ta.y + qa[j].z*ta.z + qa[j].w*ta.w
                  + qb[j].x*tb.x + qb[j].y*tb.y + qb[j].z*tb.z + qb[j].w*tb.w
                  - SHIFT;
            }
        }

#pragma unroll 2
        for (int row = 0; row < 8; ++row) {
            const int y2 = rowhalf * 24 + R * 8 + row;
#pragma unroll
            for (int c = 0; c < 3; ++c) {
                const int base = (y2 * 3 + c) * 16;     // wave-uniform
                const float4 k0 = *(const float4*)(myl + base);
                const float4 k1 = *(const float4*)(myl + base + 4);
                const float4 v0 = *(const float4*)(myl + base + 8);
                const float4 v1 = *(const float4*)(myl + base + 12);
#pragma unroll
                for (int j = 0; j < 4; ++j) {
                    float dA = fmaf(qa[j].x, k0.x, fmaf(qa[j].y, k0.y,
                               fmaf(qa[j].z, k0.z, qa[j].w * k0.w)));
                    float dB = fmaf(qb[j].x, k1.x, fmaf(qb[j].y, k1.y,
                               fmaf(qb[j].z, k1.z, qb[j].w * k1.w)));
                    const float p = __builtin_amdgcn_exp2f(
                        (qh[j][row] + qw[j][c]) + (dA + dB));
                    l[j] += p;
                    A[j][0] = fmaf(p, v0.x, A[j][0]);
                    A[j][1] = fmaf(p, v0.y, A[j][1]);
                    A[j][2] = fmaf(p, v0.z, A[j][2]);
                    A[j][3] = fmaf(p, v0.w, A[j][3]);
                    A[j][4] = fmaf(p, v1.x, A[j][4]);
                    A[j][5] = fmaf(p, v1.y, A[j][5]);
                    A[j][6] = fmaf(p, v1.z, A[j][6]);
                    A[j][7] = fmaf(p, v1.w, A[j][7]);
                }
            }
        }
    }

    // ---- two-phase in-block merge (reuse staging LDS: 2 regions) ----
    __syncthreads();   // everyone done reading staged KV
    float* mr = (float*)(lds + (wv >> 1) * 576);   // region per wave-pair
    if ((wv & 1) == 0) {
#pragma unroll
        for (int j = 0; j < 4; ++j) {
            const int q = j * 64 + lane;
            mr[q] = l[j];
#pragma unroll
            for (int e = 0; e < 8; ++e) mr[(1 + e) * 256 + q] = A[j][e];
        }
    }
    __syncthreads();
    if ((wv & 1) == 1) {
#pragma unroll
        for (int j = 0; j < 4; ++j) {
            const int q = j * 64 + lane;
            mr[q] += l[j];
#pragma unroll
            for (int e = 0; e < 8; ++e) mr[(1 + e) * 256 + q] += A[j][e];
        }
    }
    __syncthreads();

    const float* r0 = (const float*)lds;
    const float* r1 = (const float*)(lds + 576);
    float* pb = P + (size_t)(gg * NWT + wt) * PSLAB;
    for (int idx = tid; idx < PSLAB; idx += 256)
        pb[idx] = r0[idx] + r1[idx];
}

// ---------------------------------------------------------------------------
// merge: sum 8 group-partials per query, normalize, write out[b][n][h*8+j]
// ---------------------------------------------------------------------------
__global__ __launch_bounds__(256) void merge_kernel(const float* __restrict__ P,
                                                    float* __restrict__ out) {
    const int t = blockIdx.x * 256 + threadIdx.x;   // [0, 36864)
    const int wt = t >> 8, q = t & 255;
    float s[9];
#pragma unroll
    for (int j = 0; j < 9; ++j) s[j] = 0.0f;
#pragma unroll
    for (int g = 0; g < NGG; ++g) {
        const float* pb = P + (size_t)(g * NWT + wt) * PSLAB;
#pragma unroll
        for (int j = 0; j < 9; ++j) s[j] += pb[j * 256 + q];
    }
    const float inv = 1.0f / s[0];
    const int bh = wt / 9;
    const int qtl = wt - bh * 9;
    const int n = qtl * 256 + q;
    const int b = bh >> 3, h = bh & 7;
    float* op = out + ((size_t)(b * NQ + n) * 64 + h * 8);
    ((float4*)op)[0] = make_float4(s[1]*inv, s[2]*inv, s[3]*inv, s[4]*inv);
    ((float4*)op)[1] = make_float4(s[5]*inv, s[6]*inv, s[7]*inv, s[8]*inv);
}

extern "C" void kernel_launch(void* const* d_in, const int* in_sizes, int n_in,
                              void* d_out, int out_size, void* d_ws, size_t ws_size,
                              hipStream_t stream) {
    const float* in   = (const float*)d_in[0];
    const float* relw = (const float*)d_in[1];
    const float* relh = (const float*)d_in[2];
    float* P   = (float*)d_ws;    // 8 * 144 * 2304 * 4 B = 10.6 MB (proven fit)
    float* out = (float*)d_out;

    attn_kernel<<<16 * 9 * 8, 256, 0, stream>>>(in, relw, relh, P);
    merge_kernel<<<144, 256, 0, stream>>>(P, out);
}

// Round 12
// 141.155 us; speedup vs baseline: 7.6441x; 7.6441x over previous
//
#include <hip/hip_runtime.h>
#include <stdint.h>

#define WW 48
#define NQ 2304             // 48*48
#define NWT 144             // (bh, qt) tiles of 256 queries
#define NGG 8               // kc-pair groups (block covers 2 kc chunks)
#define SCL 0.51011868f     // 8^-0.5 * log2(e)  (folded so softmax = exp2)
#define SHIFT 17.312340491f // 12 * log2(e)      (fixed-shift softmax)
#define PSLAB 2304          // 9*256 floats per (gg, wt) slab

// ---------------------------------------------------------------------------
// attn: 4 queries/lane, LDS-broadcast KV (R5-verified delivery), row-split
// waves for TLP. Block = 4 waves over the SAME 256-query tile:
//   wave wv -> kc_local = wv>>1 (chunk of 3 key-cols), rowhalf = wv&1.
// grid 1152 = 16 bh * 9 qt * 8 gg -> 4608 waves = 4.5/SIMD.
// __launch_bounds__(256, 2): R10 proved this budget compiles to exactly
// 128 VGPR with ZERO spill (R11's (256,4) made the allocator pick a 64-VGPR
// budget -> 3.8 GB scratch traffic -> 1 ms). 128 VGPR still allows 4
// waves/EU in HW; occupancy now comes from the grid, not the budget.
// Block stages 2 chunks (48 rows x 3 cols x 64 B = 18.4 KB) cooperatively;
// keys consumed via wave-uniform ds_read_b128 broadcast (conflict-free).
// qh batched per 8-row round from global relh (L1-hot).
// logit = q.k + q.rel_w[x2-x+47] + q.rel_h[y2-y+47]; p = exp2(logit'-SHIFT)
// Two-phase in-block merge (LDS reuse, 2 regions) -> P slab per (gg, wt).
// ---------------------------------------------------------------------------
__global__ __launch_bounds__(256, 2) void attn_kernel(const float* __restrict__ in,
                                                      const float* __restrict__ relw,
                                                      const float* __restrict__ relh,
                                                      float* __restrict__ P) {
    __shared__ float4 lds[1152];       // 18432 B: staging, later 2 merge regions

    const int bx = blockIdx.x;
    const int bh = bx / 72;
    const int rem = bx - bh * 72;
    const int qt = rem >> 3;           // 0..8
    const int gg = rem & 7;            // 0..7  -> kc = gg*2 + kc_local
    const int tid = threadIdx.x;
    const int lane = tid & 63;
    const int wv = tid >> 6;           // 0..3
    const int kc_local = wv >> 1;
    const int rowhalf = wv & 1;
    const int kc = gg * 2 + kc_local;  // 0..15 (3 columns each)
    const int b = bh >> 3, h = bh & 7;
    const int wt = bh * 9 + qt;

    // ---- stage the block's 2 chunks: 48 rows x 3 cols x [K|V] each ----
    const float4* inp4 = (const float4*)in;
    for (int t = tid; t < 1152; t += 256) {
        const int chunk = t / 576, tt = t - chunk * 576;
        const int key = tt >> 2, p = tt & 3;
        const int row = key / 3, col = key - row * 3;
        const size_t px = (size_t)(b * NQ + row * 48 + (gg * 2 + chunk) * 3 + col) * 48;
        const int c4 = (p < 2) ? (16 + h * 2 + p) : (32 + h * 2 + (p - 2));
        lds[t] = inp4[px + c4];
    }

    // ---- this lane's four queries ----
    float4 qa[4], qb[4];
    int yq[4], xq[4];
#pragma unroll
    for (int j = 0; j < 4; ++j) {
        const int n = qt * 256 + j * 64 + lane;
        const int y = n / WW;
        yq[j] = y; xq[j] = n - y * WW;
        const float* qp = in + ((size_t)(b * NQ + n) * 192 + h * 8);
        float4 a = *(const float4*)qp, bb = *(const float4*)(qp + 4);
        a.x *= SCL; a.y *= SCL; a.z *= SCL; a.w *= SCL;
        bb.x *= SCL; bb.y *= SCL; bb.z *= SCL; bb.w *= SCL;
        qa[j] = a; qb[j] = bb;
    }

    // ---- qw per (query, chunk column) from global relw ----
    float qw[4][3];
#pragma unroll
    for (int j = 0; j < 4; ++j)
#pragma unroll
        for (int c = 0; c < 3; ++c) {
            const float* rw = relw + (kc * 3 + c - xq[j] + 47) * 8;
            float4 ta = *(const float4*)rw, tb = *(const float4*)(rw + 4);
            qw[j][c] = qa[j].x*ta.x + qa[j].y*ta.y + qa[j].z*ta.z + qa[j].w*ta.w
                     + qb[j].x*tb.x + qb[j].y*tb.y + qb[j].z*tb.z + qb[j].w*tb.w;
        }

    __syncthreads();   // staged KV visible to the 2 waves sharing each chunk

    float l[4] = {0, 0, 0, 0};
    float A[4][8] = {{0}};
    const float* myl = (const float*)(lds + kc_local * 576);

#pragma unroll 1
    for (int R = 0; R < 3; ++R) {
        // ---- batch qh for this round's 8 rows (global relh, L1-hot) ----
        float qh[4][8];
#pragma unroll
        for (int row = 0; row < 8; ++row) {
            const int y2 = rowhalf * 24 + R * 8 + row;
#pragma unroll
            for (int j = 0; j < 4; ++j) {
                const float* rh = relh + (y2 - yq[j] + 47) * 8;
                float4 ta = *(const float4*)rh, tb = *(const float4*)(rh + 4);
                qh[j][row] =
                    qa[j].x*ta.x + qa[j].y*ta.y + qa[j].z*ta.z + qa[j].w*ta.w
                  + qb[j].x*tb.x + qb[j].y*tb.y + qb[j].z*tb.z + qb[j].w*tb.w
                  - SHIFT;
            }
        }

#pragma unroll 2
        for (int row = 0; row < 8; ++row) {
            const int y2 = rowhalf * 24 + R * 8 + row;
#pragma unroll
            for (int c = 0; c < 3; ++c) {
                const int base = (y2 * 3 + c) * 16;     // wave-uniform
                const float4 k0 = *(const float4*)(myl + base);
                const float4 k1 = *(const float4*)(myl + base + 4);
                const float4 v0 = *(const float4*)(myl + base + 8);
                const float4 v1 = *(const float4*)(myl + base + 12);
#pragma unroll
                for (int j = 0; j < 4; ++j) {
                    float dA = fmaf(qa[j].x, k0.x, fmaf(qa[j].y, k0.y,
                               fmaf(qa[j].z, k0.z, qa[j].w * k0.w)));
                    float dB = fmaf(qb[j].x, k1.x, fmaf(qb[j].y, k1.y,
                               fmaf(qb[j].z, k1.z, qb[j].w * k1.w)));
                    const float p = __builtin_amdgcn_exp2f(
                        (qh[j][row] + qw[j][c]) + (dA + dB));
                    l[j] += p;
                    A[j][0] = fmaf(p, v0.x, A[j][0]);
                    A[j][1] = fmaf(p, v0.y, A[j][1]);
                    A[j][2] = fmaf(p, v0.z, A[j][2]);
                    A[j][3] = fmaf(p, v0.w, A[j][3]);
                    A[j][4] = fmaf(p, v1.x, A[j][4]);
                    A[j][5] = fmaf(p, v1.y, A[j][5]);
                    A[j][6] = fmaf(p, v1.z, A[j][6]);
                    A[j][7] = fmaf(p, v1.w, A[j][7]);
                }
            }
        }
    }

    // ---- two-phase in-block merge (reuse staging LDS: 2 regions) ----
    __syncthreads();   // everyone done reading staged KV
    float* mr = (float*)(lds + kc_local * 576);   // region per wave-pair
    if (rowhalf == 0) {
#pragma unroll
        for (int j = 0; j < 4; ++j) {
            const int q = j * 64 + lane;
            mr[q] = l[j];
#pragma unroll
            for (int e = 0; e < 8; ++e) mr[(1 + e) * 256 + q] = A[j][e];
        }
    }
    __syncthreads();
    if (rowhalf == 1) {
#pragma unroll
        for (int j = 0; j < 4; ++j) {
            const int q = j * 64 + lane;
            mr[q] += l[j];
#pragma unroll
            for (int e = 0; e < 8; ++e) mr[(1 + e) * 256 + q] += A[j][e];
        }
    }
    __syncthreads();

    const float* r0 = (const float*)lds;
    const float* r1 = (const float*)(lds + 576);
    float* pb = P + (size_t)(gg * NWT + wt) * PSLAB;
    for (int idx = tid; idx < PSLAB; idx += 256)
        pb[idx] = r0[idx] + r1[idx];
}

// ---------------------------------------------------------------------------
// merge: sum 8 group-partials per query, normalize, write out[b][n][h*8+j]
// ---------------------------------------------------------------------------
__global__ __launch_bounds__(256) void merge_kernel(const float* __restrict__ P,
                                                    float* __restrict__ out) {
    const int t = blockIdx.x * 256 + threadIdx.x;   // [0, 36864)
    const int wt = t >> 8, q = t & 255;
    float s[9];
#pragma unroll
    for (int j = 0; j < 9; ++j) s[j] = 0.0f;
#pragma unroll
    for (int g = 0; g < NGG; ++g) {
        const float* pb = P + (size_t)(g * NWT + wt) * PSLAB;
#pragma unroll
        for (int j = 0; j < 9; ++j) s[j] += pb[j * 256 + q];
    }
    const float inv = 1.0f / s[0];
    const int bh = wt / 9;
    const int qtl = wt - bh * 9;
    const int n = qtl * 256 + q;
    const int b = bh >> 3, h = bh & 7;
    float* op = out + ((size_t)(b * NQ + n) * 64 + h * 8);
    ((float4*)op)[0] = make_float4(s[1]*inv, s[2]*inv, s[3]*inv, s[4]*inv);
    ((float4*)op)[1] = make_float4(s[5]*inv, s[6]*inv, s[7]*inv, s[8]*inv);
}

extern "C" void kernel_launch(void* const* d_in, const int* in_sizes, int n_in,
                              void* d_out, int out_size, void* d_ws, size_t ws_size,
                              hipStream_t stream) {
    const float* in   = (const float*)d_in[0];
    const float* relw = (const float*)d_in[1];
    const float* relh = (const float*)d_in[2];
    float* P   = (float*)d_ws;    // 8 * 144 * 2304 * 4 B = 10.6 MB (proven fit)
    float* out = (float*)d_out;

    attn_kernel<<<16 * 9 * 8, 256, 0, stream>>>(in, relw, relh, P);
    merge_kernel<<<144, 256, 0, stream>>>(P, out);
}